// Round 3
// baseline (587.492 us; speedup 1.0000x reference)
//
#include <hip/hip_runtime.h>
#include <cstdint>

#define N_NODES 100000
#define N_EDGES 1600000
#define R_REL   5
#define NBASIS  2
#define B_START 512
#define NBUCK   256
#define BUCK_SZ 391       // 256 * 391 = 100096 >= 100000
#define EPB     6250      // edges per block in cnt/scat (256 * 6250 = 1.6M)
#define STAGE_CAP 7000    // bucket edge-count mean 6256, sd ~79
#define NBLK    1563      // ceil(100000 / 64) node-tiles

typedef __attribute__((ext_vector_type(8))) short short8;
typedef __attribute__((ext_vector_type(4))) float f32x4;

__device__ __forceinline__ unsigned short f2bf(float f) {
    unsigned u = __float_as_uint(f);
    unsigned r = (u + 0x7FFF + ((u >> 16) & 1)) >> 16;  // RNE
    return (unsigned short)r;
}
__device__ __forceinline__ float bf2f(unsigned short u) {
    return __uint_as_float(((unsigned)u) << 16);
}

// ---------------- scatter-free CSR build ------------------------------------

__global__ __launch_bounds__(256) void k_cntb(
    const int* __restrict__ ei, int* __restrict__ bhist) {
    __shared__ int lh[NBUCK];
    int tid = threadIdx.x;
    lh[tid] = 0;
    __syncthreads();
    int base = blockIdx.x * EPB;
    for (int j = tid; j < EPB; j += 256) {
        int dst = ei[N_EDGES + base + j];
        atomicAdd(&lh[dst / BUCK_SZ], 1);
    }
    __syncthreads();
    bhist[blockIdx.x * NBUCK + tid] = lh[tid];
}

__global__ __launch_bounds__(256) void k_colscan(
    int* __restrict__ bhist, int* __restrict__ colsum) {
    __shared__ int s[256];
    int b = blockIdx.x, i = threadIdx.x;
    int v = bhist[i * NBUCK + b];
    s[i] = v;
    __syncthreads();
    for (int o = 1; o < 256; o <<= 1) {
        int t = (i >= o) ? s[i - o] : 0;
        __syncthreads();
        s[i] += t;
        __syncthreads();
    }
    bhist[i * NBUCK + b] = s[i] - v;
    if (i == 255) colsum[b] = s[255];
}

__global__ __launch_bounds__(256) void k_tiny(
    const int* __restrict__ colsum, int* __restrict__ bbase) {
    __shared__ int s[256];
    int i = threadIdx.x;
    int v = colsum[i];
    s[i] = v;
    __syncthreads();
    for (int o = 1; o < 256; o <<= 1) {
        int t = (i >= o) ? s[i - o] : 0;
        __syncthreads();
        s[i] += t;
        __syncthreads();
    }
    bbase[i] = s[i] - v;
    if (i == 255) bbase[NBUCK] = s[255];
}

// record = src | et<<17 | dst_local<<20
__global__ __launch_bounds__(256) void k_scat(
    const int* __restrict__ ei, const int* __restrict__ et,
    const int* __restrict__ bhist, const int* __restrict__ bbase,
    int* __restrict__ arena) {
    __shared__ int lc[NBUCK];
    int tid = threadIdx.x;
    lc[tid] = bhist[blockIdx.x * NBUCK + tid] + bbase[tid];
    __syncthreads();
    int base = blockIdx.x * EPB;
    for (int j = tid; j < EPB; j += 256) {
        int e   = base + j;
        int src = ei[e];
        int dst = ei[N_EDGES + e];
        int t   = et[e];
        int bk  = dst / BUCK_SZ;
        int dl  = dst - bk * BUCK_SZ;
        int pos = atomicAdd(&lc[bk], 1);
        arena[pos] = src | (t << 17) | (dl << 20);
    }
}

// builds (dst, et)-sorted CSR: pk_m = src per edge, degpk = packed 6-bit
// per-(dst,et) counts, nv5 = 1/max(cnt,1).
__global__ __launch_bounds__(256) void k_build(
    const int* __restrict__ arena, const int* __restrict__ bbase,
    int* __restrict__ off, int* __restrict__ pk_m, float* __restrict__ nv5,
    unsigned* __restrict__ degpk) {
    __shared__ int deg5[BUCK_SZ * R_REL];
    __shared__ int loff[BUCK_SZ + 1];
    __shared__ int cur5[BUCK_SZ * R_REL];
    __shared__ int stg[STAGE_CAP];
    __shared__ int tsum[256];
    int b = blockIdx.x, tid = threadIdx.x;
    int base = bbase[b], end = bbase[b + 1];
    int count = end - base;
    for (int i = tid; i < BUCK_SZ * R_REL; i += 256) deg5[i] = 0;
    __syncthreads();
    for (int i = tid; i < count; i += 256) {
        int r  = arena[base + i];
        int dl = ((unsigned)r) >> 20;
        int t  = (r >> 17) & 7;
        atomicAdd(&deg5[dl * R_REL + t], 1);
    }
    __syncthreads();
    for (int dl = tid; dl < BUCK_SZ; dl += 256) {
        loff[dl] = deg5[dl * R_REL + 0] + deg5[dl * R_REL + 1] +
                   deg5[dl * R_REL + 2] + deg5[dl * R_REL + 3] +
                   deg5[dl * R_REL + 4];
    }
    __syncthreads();
    int d0 = 2 * tid, d1 = 2 * tid + 1;
    int va = (d0 < BUCK_SZ) ? loff[d0] : 0;
    int vb = (d1 < BUCK_SZ) ? loff[d1] : 0;
    tsum[tid] = va + vb;
    __syncthreads();
    for (int o = 1; o < 256; o <<= 1) {
        int v = (tid >= o) ? tsum[tid - o] : 0;
        __syncthreads();
        tsum[tid] += v;
        __syncthreads();
    }
    int pre = tsum[tid] - (va + vb);
    if (d0 < BUCK_SZ) loff[d0] = pre;
    if (d1 < BUCK_SZ) loff[d1] = pre + va;
    __syncthreads();
    for (int dl = tid; dl < BUCK_SZ; dl += 256) {
        int nn = b * BUCK_SZ + dl;
        int run = loff[dl];
        unsigned dp = 0;
#pragma unroll
        for (int t = 0; t < R_REL; t++) {
            cur5[dl * R_REL + t] = run;
            int c = deg5[dl * R_REL + t];
            run += c;
            int cc = c > 63 ? 63 : c;
            dp |= ((unsigned)cc) << (6 * t);
        }
        if (nn < N_NODES) {
            off[nn]   = base + loff[dl];
            degpk[nn] = dp;
#pragma unroll
            for (int t = 0; t < R_REL; t++) {
                int c = deg5[dl * R_REL + t];
                nv5[nn * R_REL + t] = 1.0f / (float)(c > 0 ? c : 1);
            }
        }
    }
    if (b == NBUCK - 1 && tid == 0) off[N_NODES] = N_EDGES;
    __syncthreads();
    for (int i = tid; i < count; i += 256) {
        int r  = arena[base + i];
        int dl = ((unsigned)r) >> 20;
        int t  = (r >> 17) & 7;
        int rk = atomicAdd(&cur5[dl * R_REL + t], 1);
        if (rk < STAGE_CAP) stg[rk] = r;
    }
    __syncthreads();
    for (int i = tid; i < count; i += 256) {
        int r = stg[i < STAGE_CAP ? i : STAGE_CAP - 1];
        pk_m[base + i] = r & 0x1FFFF;     // src only; et implied by sort
    }
}

// ---------------- weight fragment prep (once, 4 blocks) ---------------------
// Layers 1-3: Wf[l][ot][s][lane][j], s: 0-4 Whi(r), 5-9 Wlo(r), 10 root_hi,
// 11 root_lo.  B-frag: col = ot*16 + lane%16, k = (lane/16)*8 + j.
// Layer 0 (block 3): combined [32][32] (k<20: basis-mix r*4+i, 20-23: root0,
// pad 0), s0 = hi, s1 = lo.

__global__ __launch_bounds__(256) void k_wprep(
    const float* __restrict__ basis, const float* __restrict__ comp,
    const float* __restrict__ root,  const float* __restrict__ basis0,
    const float* __restrict__ comp0, const float* __restrict__ root0,
    unsigned short* __restrict__ wf, unsigned short* __restrict__ wf0) {
    __shared__ float lw[5120];
    int tid = threadIdx.x;
    int l = blockIdx.x;
    if (l < 3) {
        for (int idx = tid; idx < 5120; idx += 256) {
            int r = idx >> 10, rem = idx & 1023, i = rem >> 5, o = rem & 31;
            lw[idx] = comp[l * 10 + r * 2 + 0] * basis[l * 2048 + i * 32 + o]
                    + comp[l * 10 + r * 2 + 1] * basis[l * 2048 + 1024 + i * 32 + o];
        }
        __syncthreads();
        for (int idx = tid; idx < 12288; idx += 256) {
            int j = idx & 7, ln = (idx >> 3) & 63;
            int s = (idx >> 9) % 12, ot = idx / 6144;
            int o = ot * 16 + (ln & 15), kk = (ln >> 4) * 8 + j;
            float val;
            if (s < 10) val = lw[(s % 5) * 1024 + kk * 32 + o];
            else        val = root[l * 1024 + kk * 32 + o];
            unsigned short hi = f2bf(val);
            unsigned short ov = ((s >= 5 && s < 10) || s == 11)
                                ? f2bf(val - bf2f(hi)) : hi;
            wf[l * 12288 + idx] = ov;
        }
    } else {
        for (int idx = tid; idx < 1024; idx += 256) {
            int k = idx >> 5, o = idx & 31;
            float val = 0.f;
            if (k < 20) {
                int r = k >> 2, i = k & 3;
                val = comp0[r * 2 + 0] * basis0[i * 32 + o]
                    + comp0[r * 2 + 1] * basis0[128 + i * 32 + o];
            } else if (k < 24) val = root0[(k - 20) * 32 + o];
            lw[idx] = val;
        }
        __syncthreads();
        for (int idx = tid; idx < 2048; idx += 256) {
            int j = idx & 7, ln = (idx >> 3) & 63;
            int s = (idx >> 9) & 1, ot = idx >> 10;
            int o = ot * 16 + (ln & 15), kk = (ln >> 4) * 8 + j;
            float val = lw[kk * 32 + o];
            unsigned short hi = f2bf(val);
            wf0[idx] = s ? f2bf(val - bf2f(hi)) : hi;
        }
    }
}

// ---------------- layer-0 input prep: hb0[n][4] = bf16(x) ------------------

__global__ __launch_bounds__(256) void k_cvt0(
    const float* __restrict__ x, unsigned short* __restrict__ hb0) {
    int n = blockIdx.x * 256 + threadIdx.x;
    if (n >= N_NODES) return;
    float4 xv = *(const float4*)(x + (size_t)n * 4);
    unsigned short h0 = f2bf(xv.x), h1 = f2bf(xv.y), h2 = f2bf(xv.z), h3 = f2bf(xv.w);
    unsigned long long ph = (unsigned long long)h0 | ((unsigned long long)h1 << 16)
                          | ((unsigned long long)h2 << 32) | ((unsigned long long)h3 << 48);
    *(unsigned long long*)(hb0 + (size_t)n * 4) = ph;
}

// ---------------- fused layer: gather -> LDS A-tile -> MFMA -> h ------------
// Block = 64 nodes. Phase 1: 8 half-wave groups x 8 nodes; per node walk the
// 5 (dst,et)-sorted segments; 4 edge slots x 8 lanes, uint2 (4ch) gathers,
// nv folded into the mask multiplier; flush double-bf16 row into LDS
// (stride 328 shorts: 656B = 164 dw, 164%32=4 -> bank-spread ds_read_b128).
// Phase 2: 4 waves x one 16-node MFMA tile (verified k_gemm body), writes
// h (fp32) + hbout (bf16, double-buffered across layers).

__global__ __launch_bounds__(256) void k_layer(
    const unsigned short* __restrict__ hb, const int* __restrict__ pk_m,
    const float* __restrict__ nv5, const unsigned* __restrict__ degpk,
    const int* __restrict__ off, const unsigned short* __restrict__ wfl,
    const float* __restrict__ biasL, float* __restrict__ h,
    unsigned short* __restrict__ hbout) {
    __shared__ unsigned short At[64 * 328];
    int tid = threadIdx.x;
    int lane32 = tid & 31;
    int g = tid >> 5;
    int cpos = lane32 & 7;   // uint2 (4 channels) within 64B row
    int slot = lane32 >> 3;  // edge slot 0..3
    const uint2* __restrict__ hb2 = (const uint2*)hb;

    for (int i = 0; i < 8; i++) {
        int nl = g * 8 + i;
        int n = blockIdx.x * 64 + nl;
        int e0 = 0;
        unsigned dp = 0;
        if (n < N_NODES) { e0 = off[n]; dp = degpk[n]; }
        int chunkbase = e0;
        int mreg = (chunkbase + lane32 < N_EDGES) ? pk_m[chunkbase + lane32] : 0;
        int e = e0;
#pragma unroll
        for (int r = 0; r < R_REL; r++) {
            int cnt = (int)((dp >> (6 * r)) & 63u);
            float nv = (n < N_NODES) ? nv5[n * R_REL + r] : 0.f;
            float a0 = 0.f, a1 = 0.f, a2 = 0.f, a3 = 0.f;
            for (int kb = 0; kb < cnt; kb += 4) {
                if (e + kb + 3 >= chunkbase + 32) {
                    chunkbase = e + kb;
                    mreg = (chunkbase + lane32 < N_EDGES) ? pk_m[chunkbase + lane32] : 0;
                }
                int kq = kb + slot;
                int mq = __shfl(mreg, e + kq - chunkbase, 32);
                uint2 u = hb2[(size_t)mq * 8 + cpos];
                float msk = (kq < cnt) ? nv : 0.f;
                a0 += msk * __uint_as_float(u.x << 16);
                a1 += msk * __uint_as_float(u.x & 0xFFFF0000u);
                a2 += msk * __uint_as_float(u.y << 16);
                a3 += msk * __uint_as_float(u.y & 0xFFFF0000u);
            }
            e += cnt;
            a0 += __shfl_xor(a0, 8, 32);  a0 += __shfl_xor(a0, 16, 32);
            a1 += __shfl_xor(a1, 8, 32);  a1 += __shfl_xor(a1, 16, 32);
            a2 += __shfl_xor(a2, 8, 32);  a2 += __shfl_xor(a2, 16, 32);
            a3 += __shfl_xor(a3, 8, 32);  a3 += __shfl_xor(a3, 16, 32);
            if (slot == 0) {
                unsigned short h0 = f2bf(a0), h1 = f2bf(a1), h2 = f2bf(a2), h3 = f2bf(a3);
                unsigned short l0 = f2bf(a0 - bf2f(h0)), l1 = f2bf(a1 - bf2f(h1));
                unsigned short l2 = f2bf(a2 - bf2f(h2)), l3 = f2bf(a3 - bf2f(h3));
                uint2 hv, lv;
                hv.x = (unsigned)h0 | ((unsigned)h1 << 16);
                hv.y = (unsigned)h2 | ((unsigned)h3 << 16);
                lv.x = (unsigned)l0 | ((unsigned)l1 << 16);
                lv.y = (unsigned)l2 | ((unsigned)l3 << 16);
                *(uint2*)&At[nl * 328 + r * 32 + cpos * 4] = hv;
                *(uint2*)&At[nl * 328 + 160 + r * 32 + cpos * 4] = lv;
            }
        }
    }
    __syncthreads();

    int wid = tid >> 6, lane = tid & 63;
    int n0 = blockIdx.x * 64 + wid * 16;
    int row = lane & 15, kg = lane >> 4;
    const short8* arl = (const short8*)&At[(wid * 16 + row) * 328 + kg * 8];
    const short8* wv = (const short8*)wfl;
    short8 hbf = *(const short8*)(hb + (size_t)(n0 + row) * 32 + kg * 8);
    f32x4 c0 = {0.f, 0.f, 0.f, 0.f}, c1 = {0.f, 0.f, 0.f, 0.f};
#pragma unroll
    for (int s = 0; s < 5; s++) {
        short8 a = arl[s * 4];
        c0 = __builtin_amdgcn_mfma_f32_16x16x32_bf16(a, wv[s * 64 + lane], c0, 0, 0, 0);
        c1 = __builtin_amdgcn_mfma_f32_16x16x32_bf16(a, wv[(12 + s) * 64 + lane], c1, 0, 0, 0);
        c0 = __builtin_amdgcn_mfma_f32_16x16x32_bf16(a, wv[(5 + s) * 64 + lane], c0, 0, 0, 0);
        c1 = __builtin_amdgcn_mfma_f32_16x16x32_bf16(a, wv[(17 + s) * 64 + lane], c1, 0, 0, 0);
        short8 al = arl[20 + s * 4];
        c0 = __builtin_amdgcn_mfma_f32_16x16x32_bf16(al, wv[s * 64 + lane], c0, 0, 0, 0);
        c1 = __builtin_amdgcn_mfma_f32_16x16x32_bf16(al, wv[(12 + s) * 64 + lane], c1, 0, 0, 0);
    }
    c0 = __builtin_amdgcn_mfma_f32_16x16x32_bf16(hbf, wv[10 * 64 + lane], c0, 0, 0, 0);
    c1 = __builtin_amdgcn_mfma_f32_16x16x32_bf16(hbf, wv[22 * 64 + lane], c1, 0, 0, 0);
    c0 = __builtin_amdgcn_mfma_f32_16x16x32_bf16(hbf, wv[11 * 64 + lane], c0, 0, 0, 0);
    c1 = __builtin_amdgcn_mfma_f32_16x16x32_bf16(hbf, wv[23 * 64 + lane], c1, 0, 0, 0);
    float b0 = biasL[row], b1 = biasL[16 + row];
#pragma unroll
    for (int i = 0; i < 4; i++) {
        int n = n0 + kg * 4 + i;
        if (n < N_NODES) {
            float t0 = tanhf(c0[i] + b0);
            float t1 = tanhf(c1[i] + b1);
            h[(size_t)n * 32 + row]      = t0;
            h[(size_t)n * 32 + 16 + row] = t1;
            hbout[(size_t)n * 32 + row]      = f2bf(t0);
            hbout[(size_t)n * 32 + 16 + row] = f2bf(t1);
        }
    }
}

// Fused layer 0: IN=4 rows; A-tile [64][72]: cols 0-19 agg hi (r*4+c),
// 20-23 x_hi, 24-31 zero, 32-51 agg lo, 52-55 x_lo, 56-63 zero.

__global__ __launch_bounds__(256) void k_layer0(
    const unsigned short* __restrict__ hb0, const float* __restrict__ x,
    const int* __restrict__ pk_m, const float* __restrict__ nv5,
    const unsigned* __restrict__ degpk, const int* __restrict__ off,
    const unsigned short* __restrict__ wf0, const float* __restrict__ biasL,
    float* __restrict__ h, unsigned short* __restrict__ hbout) {
    __shared__ unsigned short At[64 * 72];
    int tid = threadIdx.x;
    int lane32 = tid & 31;
    int g = tid >> 5;
    int c = lane32 & 3;      // channel
    int slot = lane32 >> 2;  // edge slot 0..7

    for (int i = 0; i < 8; i++) {
        int nl = g * 8 + i;
        int n = blockIdx.x * 64 + nl;
        int e0 = 0;
        unsigned dp = 0;
        if (n < N_NODES) { e0 = off[n]; dp = degpk[n]; }
        int chunkbase = e0;
        int mreg = (chunkbase + lane32 < N_EDGES) ? pk_m[chunkbase + lane32] : 0;
        int e = e0;
#pragma unroll
        for (int r = 0; r < R_REL; r++) {
            int cnt = (int)((dp >> (6 * r)) & 63u);
            float nv = (n < N_NODES) ? nv5[n * R_REL + r] : 0.f;
            float acc = 0.f;
            for (int kb = 0; kb < cnt; kb += 8) {
                if (e + kb + 7 >= chunkbase + 32) {
                    chunkbase = e + kb;
                    mreg = (chunkbase + lane32 < N_EDGES) ? pk_m[chunkbase + lane32] : 0;
                }
                int kq = kb + slot;
                int mq = __shfl(mreg, e + kq - chunkbase, 32);
                unsigned short u = hb0[(size_t)mq * 4 + c];
                float msk = (kq < cnt) ? nv : 0.f;
                acc += msk * bf2f(u);
            }
            e += cnt;
            acc += __shfl_xor(acc, 4, 32);
            acc += __shfl_xor(acc, 8, 32);
            acc += __shfl_xor(acc, 16, 32);
            if (slot == 0) {
                unsigned short hi = f2bf(acc);
                unsigned short lo = f2bf(acc - bf2f(hi));
                At[nl * 72 + r * 4 + c]      = hi;
                At[nl * 72 + 32 + r * 4 + c] = lo;
            }
        }
        // x part + zero pad
        if (lane32 < 4) {
            float xv = (n < N_NODES) ? x[(size_t)n * 4 + lane32] : 0.f;
            unsigned short hi = f2bf(xv);
            unsigned short lo = f2bf(xv - bf2f(hi));
            At[nl * 72 + 20 + lane32] = hi;
            At[nl * 72 + 52 + lane32] = lo;
        } else if (lane32 < 12) {
            At[nl * 72 + 20 + lane32] = 0;
            At[nl * 72 + 52 + lane32] = 0;
        }
    }
    __syncthreads();

    int wid = tid >> 6, lane = tid & 63;
    int n0 = blockIdx.x * 64 + wid * 16;
    int row = lane & 15, kg = lane >> 4;
    const short8* arl = (const short8*)&At[(wid * 16 + row) * 72 + kg * 8];
    const short8* wv = (const short8*)wf0;
    short8 a01 = arl[0], a23 = arl[4];
    f32x4 c0 = {0.f, 0.f, 0.f, 0.f}, c1 = {0.f, 0.f, 0.f, 0.f};
    c0 = __builtin_amdgcn_mfma_f32_16x16x32_bf16(a01, wv[0 * 64 + lane], c0, 0, 0, 0);
    c1 = __builtin_amdgcn_mfma_f32_16x16x32_bf16(a01, wv[2 * 64 + lane], c1, 0, 0, 0);
    c0 = __builtin_amdgcn_mfma_f32_16x16x32_bf16(a01, wv[1 * 64 + lane], c0, 0, 0, 0);
    c1 = __builtin_amdgcn_mfma_f32_16x16x32_bf16(a01, wv[3 * 64 + lane], c1, 0, 0, 0);
    c0 = __builtin_amdgcn_mfma_f32_16x16x32_bf16(a23, wv[0 * 64 + lane], c0, 0, 0, 0);
    c1 = __builtin_amdgcn_mfma_f32_16x16x32_bf16(a23, wv[2 * 64 + lane], c1, 0, 0, 0);
    float b0 = biasL[row], b1 = biasL[16 + row];
#pragma unroll
    for (int i = 0; i < 4; i++) {
        int n = n0 + kg * 4 + i;
        if (n < N_NODES) {
            float t0 = tanhf(c0[i] + b0);
            float t1 = tanhf(c1[i] + b1);
            h[(size_t)n * 32 + row]      = t0;
            h[(size_t)n * 32 + 16 + row] = t1;
            hbout[(size_t)n * 32 + row]      = f2bf(t0);
            hbout[(size_t)n * 32 + 16 + row] = f2bf(t1);
        }
    }
}

// ---------------- start-node row save + MLP head ----------------

__global__ void k_save(const float* __restrict__ h, const int* __restrict__ start,
                       float* __restrict__ sav) {
    int t = blockIdx.x * blockDim.x + threadIdx.x;
    if (t < B_START * 32) {
        int b = t >> 5, ln = t & 31;
        sav[t] = h[(size_t)start[b] * 32 + ln];
    }
}

__global__ __launch_bounds__(128) void k_mlp(
    const float* __restrict__ sav, const float* __restrict__ w1,
    const float* __restrict__ b1, const float* __restrict__ w2,
    const float* __restrict__ b2, float* __restrict__ out) {
    __shared__ float cvec[128];
    __shared__ float hb[128];
    __shared__ float lg[8];
    int b = blockIdx.x, t = threadIdx.x;
    cvec[t] = sav[(t >> 5) * (B_START * 32) + b * 32 + (t & 31)];
    __syncthreads();
    float a = b1[t];
#pragma unroll 8
    for (int k = 0; k < 128; k++) a += cvec[k] * w1[k * 128 + t];
    hb[t] = fmaxf(a, 0.f);
    __syncthreads();
    if (t < 5) {
        float a2 = b2[t];
        for (int k = 0; k < 128; k++) a2 += hb[k] * w2[k * 5 + t];
        lg[t] = a2;
    }
    __syncthreads();
    if (t < 5) {
        float m = lg[0];
        for (int j = 1; j < 5; j++) m = fmaxf(m, lg[j]);
        float s = 0.f;
        for (int j = 0; j < 5; j++) s += expf(lg[j] - m);
        out[b * 5 + t] = lg[t] - m - logf(s);
    }
}

// ---------------- launch ----------------

extern "C" void kernel_launch(void* const* d_in, const int* in_sizes, int n_in,
                              void* d_out, int out_size, void* d_ws, size_t ws_size,
                              hipStream_t stream) {
    const float* x      = (const float*)d_in[0];
    const int*   ei     = (const int*)d_in[1];
    const int*   etype  = (const int*)d_in[2];
    const int*   start  = (const int*)d_in[3];
    const float* basis0 = (const float*)d_in[4];
    const float* comp0  = (const float*)d_in[5];
    const float* root0  = (const float*)d_in[6];
    const float* bias0  = (const float*)d_in[7];
    const float* basis  = (const float*)d_in[8];
    const float* comp   = (const float*)d_in[9];
    const float* root   = (const float*)d_in[10];
    const float* bias   = (const float*)d_in[11];
    const float* w1     = (const float*)d_in[12];
    const float* b1     = (const float*)d_in[13];
    const float* w2     = (const float*)d_in[14];
    const float* b2     = (const float*)d_in[15];
    float* out = (float*)d_out;

    char* p = (char*)d_ws;
    auto alloc = [&](size_t bytes) -> void* {
        void* r = (void*)p;
        p += (bytes + 255) & ~(size_t)255;
        return r;
    };
    int*            bhist  = (int*)alloc((size_t)NBUCK * NBUCK * 4);
    int*            colsum = (int*)alloc(NBUCK * 4);
    int*            bbase  = (int*)alloc((NBUCK + 1) * 4);
    int*            arena  = (int*)alloc((size_t)N_EDGES * 4);
    int*            off    = (int*)alloc((N_NODES + 1) * 4);
    int*            pk_m   = (int*)alloc((size_t)N_EDGES * 4);
    float*          nv5    = (float*)alloc((size_t)N_NODES * R_REL * 4);
    unsigned*       degpk  = (unsigned*)alloc((size_t)N_NODES * 4);
    float*          h      = (float*)alloc((size_t)N_NODES * 32 * 4);
    unsigned short* hbA    = (unsigned short*)alloc((size_t)(N_NODES + 64) * 32 * 2);
    unsigned short* hbB    = (unsigned short*)alloc((size_t)(N_NODES + 64) * 32 * 2);
    unsigned short* hb0    = (unsigned short*)alloc((size_t)N_NODES * 4 * 2);
    unsigned short* wf     = (unsigned short*)alloc((size_t)3 * 12288 * 2);
    unsigned short* wf0    = (unsigned short*)alloc((size_t)2048 * 2);
    float*          sav    = (float*)alloc(4 * B_START * 32 * 4);

    k_cntb<<<NBUCK, 256, 0, stream>>>(ei, bhist);
    k_colscan<<<NBUCK, 256, 0, stream>>>(bhist, colsum);
    k_tiny<<<1, 256, 0, stream>>>(colsum, bbase);
    k_scat<<<NBUCK, 256, 0, stream>>>(ei, etype, bhist, bbase, arena);
    k_build<<<NBUCK, 256, 0, stream>>>(arena, bbase, off, pk_m, nv5, degpk);
    k_wprep<<<4, 256, 0, stream>>>(basis, comp, root, basis0, comp0, root0, wf, wf0);
    k_cvt0<<<(N_NODES + 255) / 256, 256, 0, stream>>>(x, hb0);

    // layer 0 (in=4): writes hbA
    k_layer0<<<NBLK, 256, 0, stream>>>(hb0, x, pk_m, nv5, degpk, off, wf0, bias0, h, hbA);
    k_save<<<64, 256, 0, stream>>>(h, start, sav);
    // layers 1..3 (in=32): ping-pong hbA/hbB (fused kernel can't write in-place)
    unsigned short* hin = hbA;
    unsigned short* hout = hbB;
    for (int l = 0; l < 3; l++) {
        k_layer<<<NBLK, 256, 0, stream>>>(hin, pk_m, nv5, degpk, off,
                                          wf + (size_t)l * 12288, bias + l * 32,
                                          h, hout);
        k_save<<<64, 256, 0, stream>>>(h, start, sav + (l + 1) * 16384);
        unsigned short* t = hin; hin = hout; hout = t;
    }

    k_mlp<<<B_START, 128, 0, stream>>>(sav, w1, b1, w2, b2, out);
}

// Round 4
// 380.073 us; speedup vs baseline: 1.5457x; 1.5457x over previous
//
#include <hip/hip_runtime.h>
#include <cstdint>

#define N_NODES 100000
#define N_EDGES 1600000
#define R_REL   5
#define NBASIS  2
#define B_START 512
#define PART_SZ 12500     // 8 * 12500 = 100000 (gather swizzle)
#define NBUCK   256
#define BUCK_SZ 391       // 256 * 391 = 100096 >= 100000
#define EPB     6250      // edges per block in cnt/scat (256 * 6250 = 1.6M)
#define STAGE_CAP 7000    // bucket edge-count mean 6256, sd ~79

typedef __attribute__((ext_vector_type(8))) short short8;
typedef __attribute__((ext_vector_type(4))) float f32x4;
typedef _Float16 half8 __attribute__((ext_vector_type(8)));

__device__ __forceinline__ unsigned short f2bf(float f) {
    unsigned u = __float_as_uint(f);
    unsigned r = (u + 0x7FFF + ((u >> 16) & 1)) >> 16;  // RNE
    return (unsigned short)r;
}
__device__ __forceinline__ float bf2f(unsigned short u) {
    return __uint_as_float(((unsigned)u) << 16);
}
__device__ __forceinline__ unsigned short f2h(float f) {
    _Float16 h = (_Float16)f;                            // RNE
    return __builtin_bit_cast(unsigned short, h);
}

// ---------------- scatter-free CSR build ------------------------------------

__global__ __launch_bounds__(256) void k_cntb(
    const int* __restrict__ ei, int* __restrict__ bhist) {
    __shared__ int lh[NBUCK];
    int tid = threadIdx.x;
    lh[tid] = 0;
    __syncthreads();
    int base = blockIdx.x * EPB;
    for (int j = tid; j < EPB; j += 256) {
        int dst = ei[N_EDGES + base + j];
        atomicAdd(&lh[dst / BUCK_SZ], 1);
    }
    __syncthreads();
    bhist[blockIdx.x * NBUCK + tid] = lh[tid];
}

__global__ __launch_bounds__(256) void k_colscan(
    int* __restrict__ bhist, int* __restrict__ colsum) {
    __shared__ int s[256];
    int b = blockIdx.x, i = threadIdx.x;
    int v = bhist[i * NBUCK + b];
    s[i] = v;
    __syncthreads();
    for (int o = 1; o < 256; o <<= 1) {
        int t = (i >= o) ? s[i - o] : 0;
        __syncthreads();
        s[i] += t;
        __syncthreads();
    }
    bhist[i * NBUCK + b] = s[i] - v;
    if (i == 255) colsum[b] = s[255];
}

__global__ __launch_bounds__(256) void k_tiny(
    const int* __restrict__ colsum, int* __restrict__ bbase) {
    __shared__ int s[256];
    int i = threadIdx.x;
    int v = colsum[i];
    s[i] = v;
    __syncthreads();
    for (int o = 1; o < 256; o <<= 1) {
        int t = (i >= o) ? s[i - o] : 0;
        __syncthreads();
        s[i] += t;
        __syncthreads();
    }
    bbase[i] = s[i] - v;
    if (i == 255) bbase[NBUCK] = s[255];
}

// record = src | et<<17 | dst_local<<20
__global__ __launch_bounds__(256) void k_scat(
    const int* __restrict__ ei, const int* __restrict__ et,
    const int* __restrict__ bhist, const int* __restrict__ bbase,
    int* __restrict__ arena) {
    __shared__ int lc[NBUCK];
    int tid = threadIdx.x;
    lc[tid] = bhist[blockIdx.x * NBUCK + tid] + bbase[tid];
    __syncthreads();
    int base = blockIdx.x * EPB;
    for (int j = tid; j < EPB; j += 256) {
        int e   = base + j;
        int src = ei[e];
        int dst = ei[N_EDGES + e];
        int t   = et[e];
        int bk  = dst / BUCK_SZ;
        int dl  = dst - bk * BUCK_SZ;
        int pos = atomicAdd(&lc[bk], 1);
        arena[pos] = src | (t << 17) | (dl << 20);
    }
}

// builds (dst, et)-sorted CSR: pk_m = src per edge, degpk = packed 6-bit
// per-(dst,et) counts, nv5 = 1/max(cnt,1).
__global__ __launch_bounds__(256) void k_build(
    const int* __restrict__ arena, const int* __restrict__ bbase,
    int* __restrict__ off, int* __restrict__ pk_m, float* __restrict__ nv5,
    unsigned* __restrict__ degpk) {
    __shared__ int deg5[BUCK_SZ * R_REL];
    __shared__ int loff[BUCK_SZ + 1];
    __shared__ int cur5[BUCK_SZ * R_REL];
    __shared__ int stg[STAGE_CAP];
    __shared__ int tsum[256];
    int b = blockIdx.x, tid = threadIdx.x;
    int base = bbase[b], end = bbase[b + 1];
    int count = end - base;
    for (int i = tid; i < BUCK_SZ * R_REL; i += 256) deg5[i] = 0;
    __syncthreads();
    for (int i = tid; i < count; i += 256) {
        int r  = arena[base + i];
        int dl = ((unsigned)r) >> 20;
        int t  = (r >> 17) & 7;
        atomicAdd(&deg5[dl * R_REL + t], 1);
    }
    __syncthreads();
    for (int dl = tid; dl < BUCK_SZ; dl += 256) {
        loff[dl] = deg5[dl * R_REL + 0] + deg5[dl * R_REL + 1] +
                   deg5[dl * R_REL + 2] + deg5[dl * R_REL + 3] +
                   deg5[dl * R_REL + 4];
    }
    __syncthreads();
    int d0 = 2 * tid, d1 = 2 * tid + 1;
    int va = (d0 < BUCK_SZ) ? loff[d0] : 0;
    int vb = (d1 < BUCK_SZ) ? loff[d1] : 0;
    tsum[tid] = va + vb;
    __syncthreads();
    for (int o = 1; o < 256; o <<= 1) {
        int v = (tid >= o) ? tsum[tid - o] : 0;
        __syncthreads();
        tsum[tid] += v;
        __syncthreads();
    }
    int pre = tsum[tid] - (va + vb);
    if (d0 < BUCK_SZ) loff[d0] = pre;
    if (d1 < BUCK_SZ) loff[d1] = pre + va;
    __syncthreads();
    for (int dl = tid; dl < BUCK_SZ; dl += 256) {
        int nn = b * BUCK_SZ + dl;
        int run = loff[dl];
        unsigned dp = 0;
#pragma unroll
        for (int t = 0; t < R_REL; t++) {
            cur5[dl * R_REL + t] = run;
            int c = deg5[dl * R_REL + t];
            run += c;
            int cc = c > 63 ? 63 : c;
            dp |= ((unsigned)cc) << (6 * t);
        }
        if (nn < N_NODES) {
            off[nn]   = base + loff[dl];
            degpk[nn] = dp;
#pragma unroll
            for (int t = 0; t < R_REL; t++) {
                int c = deg5[dl * R_REL + t];
                nv5[nn * R_REL + t] = 1.0f / (float)(c > 0 ? c : 1);
            }
        }
    }
    if (b == NBUCK - 1 && tid == 0) off[N_NODES] = N_EDGES;
    __syncthreads();
    for (int i = tid; i < count; i += 256) {
        int r  = arena[base + i];
        int dl = ((unsigned)r) >> 20;
        int t  = (r >> 17) & 7;
        int rk = atomicAdd(&cur5[dl * R_REL + t], 1);
        if (rk < STAGE_CAP) stg[rk] = r;
    }
    __syncthreads();
    for (int i = tid; i < count; i += 256) {
        int r = stg[i < STAGE_CAP ? i : STAGE_CAP - 1];
        pk_m[base + i] = r & 0x1FFFF;     // src only; et implied by sort
    }
}

// ---------------- weight fragment prep (once, 4 blocks) ---------------------
// Layers 1-3: wfh (f16): [l][ot(2)][s(5)][lane(64)][j(8)] relation mats;
// wfr (bf16): [l][ot(2)][hi/lo(2)][lane][j] root.
// Layer 0 (block 3): wf0 (f16) [ot(2)][lane][j]; combined K=32
// (k<20 basis-mix r*4+i, 20-23 root0, else 0).
// B-frag: col = ot*16 + lane%16, k = (lane/16)*8 + j.

__global__ __launch_bounds__(256) void k_wprep(
    const float* __restrict__ basis, const float* __restrict__ comp,
    const float* __restrict__ root,  const float* __restrict__ basis0,
    const float* __restrict__ comp0, const float* __restrict__ root0,
    unsigned short* __restrict__ wfh, unsigned short* __restrict__ wfr,
    unsigned short* __restrict__ wf0) {
    __shared__ float lw[5120];
    int tid = threadIdx.x;
    int l = blockIdx.x;
    if (l < 3) {
        for (int idx = tid; idx < 5120; idx += 256) {
            int r = idx >> 10, rem = idx & 1023, i = rem >> 5, o = rem & 31;
            lw[idx] = comp[l * 10 + r * 2 + 0] * basis[l * 2048 + i * 32 + o]
                    + comp[l * 10 + r * 2 + 1] * basis[l * 2048 + 1024 + i * 32 + o];
        }
        __syncthreads();
        for (int idx = tid; idx < 5120; idx += 256) {
            int ot = idx / 2560, rem = idx % 2560;
            int s = rem >> 9, ln = (rem >> 3) & 63, j = idx & 7;
            int o = ot * 16 + (ln & 15), kk = (ln >> 4) * 8 + j;
            wfh[l * 5120 + idx] = f2h(lw[s * 1024 + kk * 32 + o]);
        }
        for (int idx = tid; idx < 2048; idx += 256) {
            int ot = idx >> 10, s = (idx >> 9) & 1, ln = (idx >> 3) & 63, j = idx & 7;
            int o = ot * 16 + (ln & 15), kk = (ln >> 4) * 8 + j;
            float val = root[l * 1024 + kk * 32 + o];
            unsigned short hi = f2bf(val);
            wfr[l * 2048 + idx] = s ? f2bf(val - bf2f(hi)) : hi;
        }
    } else {
        for (int idx = tid; idx < 1024; idx += 256) {
            int k = idx >> 5, o = idx & 31;
            float val = 0.f;
            if (k < 20) {
                int r = k >> 2, i = k & 3;
                val = comp0[r * 2 + 0] * basis0[i * 32 + o]
                    + comp0[r * 2 + 1] * basis0[128 + i * 32 + o];
            } else if (k < 24) val = root0[(k - 20) * 32 + o];
            lw[idx] = val;
        }
        __syncthreads();
        for (int idx = tid; idx < 1024; idx += 256) {
            int ot = idx >> 9, ln = (idx >> 3) & 63, j = idx & 7;
            int o = ot * 16 + (ln & 15), kk = (ln >> 4) * 8 + j;
            wf0[idx] = f2h(lw[kk * 32 + o]);
        }
    }
}

// ---------------- layer-0 input prep: hb0[n][4] = bf16(x) ------------------

__global__ __launch_bounds__(256) void k_cvt0(
    const float* __restrict__ x, unsigned short* __restrict__ hb0) {
    int n = blockIdx.x * 256 + threadIdx.x;
    if (n >= N_NODES) return;
    float4 xv = *(const float4*)(x + (size_t)n * 4);
    unsigned short h0 = f2bf(xv.x), h1 = f2bf(xv.y), h2 = f2bf(xv.z), h3 = f2bf(xv.w);
    unsigned long long ph = (unsigned long long)h0 | ((unsigned long long)h1 << 16)
                          | ((unsigned long long)h2 << 32) | ((unsigned long long)h3 << 48);
    *(unsigned long long*)(hb0 + (size_t)n * 4) = ph;
}

// ---------------- gather (layers 1-3): half-wave per node -------------------
// lane = slot(2b)*8 + cpos(3b): 4 edges in flight, each fetched as uint2
// (4 bf16 ch) by 8 lanes. (dst,et)-sorted edges; 5 segments via degpk; nv
// folded into mask multiplier. Flush: f16 agg row [n][160] (r*32+c).
// High occupancy (12504 blocks, no LDS) hides L2/L3 gather latency.

__global__ __launch_bounds__(256) void k_gath32(
    const unsigned short* __restrict__ hb, const int* __restrict__ pk_m,
    const float* __restrict__ nv5, const unsigned* __restrict__ degpk,
    const int* __restrict__ off, unsigned short* __restrict__ agg) {
    int tid  = threadIdx.x;
    int lane32 = tid & 31;
    int sub  = tid >> 5;
    int part  = blockIdx.x & 7;
    int local = (blockIdx.x >> 3) * 8 + sub;
    if (local >= PART_SZ) return;
    int n = part * PART_SZ + local;
    int cpos = lane32 & 7;
    int slot = lane32 >> 3;
    const uint2* __restrict__ hb2 = (const uint2*)hb;

    int e0 = off[n];
    unsigned dp = degpk[n];
    int chunkbase = e0;
    int mreg = (chunkbase + lane32 < N_EDGES) ? pk_m[chunkbase + lane32] : 0;
    int e = e0;
#pragma unroll
    for (int r = 0; r < R_REL; r++) {
        int cnt = (int)((dp >> (6 * r)) & 63u);
        float nv = nv5[n * R_REL + r];
        float a0 = 0.f, a1 = 0.f, a2 = 0.f, a3 = 0.f;
        for (int kb = 0; kb < cnt; kb += 4) {
            if (e + kb + 3 >= chunkbase + 32) {
                chunkbase = e + kb;
                mreg = (chunkbase + lane32 < N_EDGES) ? pk_m[chunkbase + lane32] : 0;
            }
            int kq = kb + slot;
            int mq = __shfl(mreg, e + kq - chunkbase, 32);
            uint2 u = hb2[(size_t)mq * 8 + cpos];
            float msk = (kq < cnt) ? nv : 0.f;
            a0 += msk * __uint_as_float(u.x << 16);
            a1 += msk * __uint_as_float(u.x & 0xFFFF0000u);
            a2 += msk * __uint_as_float(u.y << 16);
            a3 += msk * __uint_as_float(u.y & 0xFFFF0000u);
        }
        e += cnt;
        a0 += __shfl_xor(a0, 8, 32);  a0 += __shfl_xor(a0, 16, 32);
        a1 += __shfl_xor(a1, 8, 32);  a1 += __shfl_xor(a1, 16, 32);
        a2 += __shfl_xor(a2, 8, 32);  a2 += __shfl_xor(a2, 16, 32);
        a3 += __shfl_xor(a3, 8, 32);  a3 += __shfl_xor(a3, 16, 32);
        if (slot == 0) {
            uint2 pk;
            pk.x = (unsigned)f2h(a0) | ((unsigned)f2h(a1) << 16);
            pk.y = (unsigned)f2h(a2) | ((unsigned)f2h(a3) << 16);
            *(uint2*)(agg + (size_t)n * 160 + r * 32 + cpos * 4) = pk;
        }
    }
}

// gather layer 0 (IN=4): lane = slot(4b)*2 + cpos(1b); 16 edges in flight,
// uint (2 bf16 ch) loads. Also fills x (f16) + zero pad cols 20-31 of a0.

__global__ __launch_bounds__(256) void k_gath0(
    const unsigned short* __restrict__ hb0, const float* __restrict__ x,
    const int* __restrict__ pk_m, const float* __restrict__ nv5,
    const unsigned* __restrict__ degpk, const int* __restrict__ off,
    unsigned short* __restrict__ a0v) {
    int tid  = threadIdx.x;
    int lane32 = tid & 31;
    int sub  = tid >> 5;
    int part  = blockIdx.x & 7;
    int local = (blockIdx.x >> 3) * 8 + sub;
    if (local >= PART_SZ) return;
    int n = part * PART_SZ + local;
    int cpos = lane32 & 1;
    int slot = lane32 >> 1;
    const unsigned* __restrict__ hb32 = (const unsigned*)hb0;

    int e0 = off[n];
    unsigned dp = degpk[n];
    int chunkbase = e0;
    int mreg = (chunkbase + lane32 < N_EDGES) ? pk_m[chunkbase + lane32] : 0;
    int e = e0;
#pragma unroll
    for (int r = 0; r < R_REL; r++) {
        int cnt = (int)((dp >> (6 * r)) & 63u);
        float nv = nv5[n * R_REL + r];
        float p0 = 0.f, p1 = 0.f;
        for (int kb = 0; kb < cnt; kb += 16) {
            if (e + kb + 15 >= chunkbase + 32) {
                chunkbase = e + kb;
                mreg = (chunkbase + lane32 < N_EDGES) ? pk_m[chunkbase + lane32] : 0;
            }
            int kq = kb + slot;
            int mq = __shfl(mreg, e + kq - chunkbase, 32);
            unsigned u = hb32[(size_t)mq * 2 + cpos];
            float msk = (kq < cnt) ? nv : 0.f;
            p0 += msk * __uint_as_float(u << 16);
            p1 += msk * __uint_as_float(u & 0xFFFF0000u);
        }
        e += cnt;
        p0 += __shfl_xor(p0, 2, 32); p0 += __shfl_xor(p0, 4, 32);
        p0 += __shfl_xor(p0, 8, 32); p0 += __shfl_xor(p0, 16, 32);
        p1 += __shfl_xor(p1, 2, 32); p1 += __shfl_xor(p1, 4, 32);
        p1 += __shfl_xor(p1, 8, 32); p1 += __shfl_xor(p1, 16, 32);
        if (slot == 0) {
            unsigned pk = (unsigned)f2h(p0) | ((unsigned)f2h(p1) << 16);
            *(unsigned*)(a0v + (size_t)n * 32 + r * 4 + cpos * 2) = pk;
        }
    }
    if (lane32 < 12) {
        float xv = (lane32 < 4) ? x[(size_t)n * 4 + lane32] : 0.f;
        a0v[(size_t)n * 32 + 20 + lane32] = (lane32 < 4) ? f2h(xv) : (unsigned short)0;
    }
}

// ---------------- dense relation transform via MFMA -------------------------
// h[n][o] = tanh( sum_r agg_r W_r (f16) + hb_prev root (double-bf16) + bias ).
// A-frag: row = lane%16, k = (lane/16)*8+j.  C: col = lane%16,
// row = (lane/16)*4+reg.  In-place hbuf write is race-free (wave-local tile).

__global__ __launch_bounds__(256) void k_gemm(
    const unsigned short* __restrict__ agg, const unsigned short* __restrict__ hbin,
    const unsigned short* __restrict__ wfhl, const unsigned short* __restrict__ wfrl,
    const float* __restrict__ biasL, float* __restrict__ h,
    unsigned short* __restrict__ hbout) {
    int tid = threadIdx.x;
    int wid = tid >> 6, lane = tid & 63;
    int tile = blockIdx.x * 4 + wid;
    if (tile >= N_NODES / 16) return;
    int n0 = tile * 16;
    int row = lane & 15, kg = lane >> 4;
    const half8* ar = (const half8*)(agg + (size_t)(n0 + row) * 160 + kg * 8);
    const half8* wh = (const half8*)wfhl;
    const short8* wr = (const short8*)wfrl;
    short8 hbf = *(const short8*)(hbin + (size_t)(n0 + row) * 32 + kg * 8);
    f32x4 c0 = {0.f, 0.f, 0.f, 0.f}, c1 = {0.f, 0.f, 0.f, 0.f};
#pragma unroll
    for (int s = 0; s < 5; s++) {
        half8 a = ar[s * 4];
        c0 = __builtin_amdgcn_mfma_f32_16x16x32_f16(a, wh[s * 64 + lane], c0, 0, 0, 0);
        c1 = __builtin_amdgcn_mfma_f32_16x16x32_f16(a, wh[320 + s * 64 + lane], c1, 0, 0, 0);
    }
    c0 = __builtin_amdgcn_mfma_f32_16x16x32_bf16(hbf, wr[lane], c0, 0, 0, 0);
    c0 = __builtin_amdgcn_mfma_f32_16x16x32_bf16(hbf, wr[64 + lane], c0, 0, 0, 0);
    c1 = __builtin_amdgcn_mfma_f32_16x16x32_bf16(hbf, wr[128 + lane], c1, 0, 0, 0);
    c1 = __builtin_amdgcn_mfma_f32_16x16x32_bf16(hbf, wr[192 + lane], c1, 0, 0, 0);
    float b0 = biasL[row], b1 = biasL[16 + row];
#pragma unroll
    for (int i = 0; i < 4; i++) {
        int n = n0 + kg * 4 + i;
        float t0 = tanhf(c0[i] + b0);
        float t1 = tanhf(c1[i] + b1);
        h[(size_t)n * 32 + row]      = t0;
        h[(size_t)n * 32 + 16 + row] = t1;
        hbout[(size_t)n * 32 + row]      = f2bf(t0);
        hbout[(size_t)n * 32 + 16 + row] = f2bf(t1);
    }
}

__global__ __launch_bounds__(256) void k_gemm0(
    const unsigned short* __restrict__ a0v, const unsigned short* __restrict__ wf0,
    const float* __restrict__ biasL, float* __restrict__ h,
    unsigned short* __restrict__ hbout) {
    int tid = threadIdx.x;
    int wid = tid >> 6, lane = tid & 63;
    int tile = blockIdx.x * 4 + wid;
    if (tile >= N_NODES / 16) return;
    int n0 = tile * 16;
    int row = lane & 15, kg = lane >> 4;
    half8 a = *(const half8*)(a0v + (size_t)(n0 + row) * 32 + kg * 8);
    const half8* wv = (const half8*)wf0;
    f32x4 c0 = {0.f, 0.f, 0.f, 0.f}, c1 = {0.f, 0.f, 0.f, 0.f};
    c0 = __builtin_amdgcn_mfma_f32_16x16x32_f16(a, wv[lane], c0, 0, 0, 0);
    c1 = __builtin_amdgcn_mfma_f32_16x16x32_f16(a, wv[64 + lane], c1, 0, 0, 0);
    float b0 = biasL[row], b1 = biasL[16 + row];
#pragma unroll
    for (int i = 0; i < 4; i++) {
        int n = n0 + kg * 4 + i;
        float t0 = tanhf(c0[i] + b0);
        float t1 = tanhf(c1[i] + b1);
        h[(size_t)n * 32 + row]      = t0;
        h[(size_t)n * 32 + 16 + row] = t1;
        hbout[(size_t)n * 32 + row]      = f2bf(t0);
        hbout[(size_t)n * 32 + 16 + row] = f2bf(t1);
    }
}

// ---------------- start-node row save + MLP head ----------------

__global__ void k_save(const float* __restrict__ h, const int* __restrict__ start,
                       float* __restrict__ sav) {
    int t = blockIdx.x * blockDim.x + threadIdx.x;
    if (t < B_START * 32) {
        int b = t >> 5, ln = t & 31;
        sav[t] = h[(size_t)start[b] * 32 + ln];
    }
}

__global__ __launch_bounds__(128) void k_mlp(
    const float* __restrict__ sav, const float* __restrict__ w1,
    const float* __restrict__ b1, const float* __restrict__ w2,
    const float* __restrict__ b2, float* __restrict__ out) {
    __shared__ float cvec[128];
    __shared__ float hb[128];
    __shared__ float lg[8];
    int b = blockIdx.x, t = threadIdx.x;
    cvec[t] = sav[(t >> 5) * (B_START * 32) + b * 32 + (t & 31)];
    __syncthreads();
    float a = b1[t];
#pragma unroll 8
    for (int k = 0; k < 128; k++) a += cvec[k] * w1[k * 128 + t];
    hb[t] = fmaxf(a, 0.f);
    __syncthreads();
    if (t < 5) {
        float a2 = b2[t];
        for (int k = 0; k < 128; k++) a2 += hb[k] * w2[k * 5 + t];
        lg[t] = a2;
    }
    __syncthreads();
    if (t < 5) {
        float m = lg[0];
        for (int j = 1; j < 5; j++) m = fmaxf(m, lg[j]);
        float s = 0.f;
        for (int j = 0; j < 5; j++) s += expf(lg[j] - m);
        out[b * 5 + t] = lg[t] - m - logf(s);
    }
}

// ---------------- launch ----------------

extern "C" void kernel_launch(void* const* d_in, const int* in_sizes, int n_in,
                              void* d_out, int out_size, void* d_ws, size_t ws_size,
                              hipStream_t stream) {
    const float* x      = (const float*)d_in[0];
    const int*   ei     = (const int*)d_in[1];
    const int*   etype  = (const int*)d_in[2];
    const int*   start  = (const int*)d_in[3];
    const float* basis0 = (const float*)d_in[4];
    const float* comp0  = (const float*)d_in[5];
    const float* root0  = (const float*)d_in[6];
    const float* bias0  = (const float*)d_in[7];
    const float* basis  = (const float*)d_in[8];
    const float* comp   = (const float*)d_in[9];
    const float* root   = (const float*)d_in[10];
    const float* bias   = (const float*)d_in[11];
    const float* w1     = (const float*)d_in[12];
    const float* b1     = (const float*)d_in[13];
    const float* w2     = (const float*)d_in[14];
    const float* b2     = (const float*)d_in[15];
    float* out = (float*)d_out;

    char* p = (char*)d_ws;
    auto alloc = [&](size_t bytes) -> void* {
        void* r = (void*)p;
        p += (bytes + 255) & ~(size_t)255;
        return r;
    };
    int*            bhist  = (int*)alloc((size_t)NBUCK * NBUCK * 4);
    int*            colsum = (int*)alloc(NBUCK * 4);
    int*            bbase  = (int*)alloc((NBUCK + 1) * 4);
    int*            arena  = (int*)alloc((size_t)N_EDGES * 4);
    int*            off    = (int*)alloc((N_NODES + 1) * 4);
    int*            pk_m   = (int*)alloc((size_t)N_EDGES * 4);
    float*          nv5    = (float*)alloc((size_t)N_NODES * R_REL * 4);
    unsigned*       degpk  = (unsigned*)alloc((size_t)N_NODES * 4);
    float*          h      = (float*)alloc((size_t)N_NODES * 32 * 4);
    unsigned short* hbuf   = (unsigned short*)alloc((size_t)(N_NODES + 64) * 32 * 2);
    unsigned short* hb0    = (unsigned short*)alloc((size_t)N_NODES * 4 * 2);
    unsigned short* a0v    = (unsigned short*)alloc((size_t)(N_NODES + 64) * 32 * 2);
    unsigned short* agg    = (unsigned short*)alloc((size_t)(N_NODES + 64) * 160 * 2);
    unsigned short* wfh    = (unsigned short*)alloc((size_t)3 * 5120 * 2);
    unsigned short* wfr    = (unsigned short*)alloc((size_t)3 * 2048 * 2);
    unsigned short* wf0    = (unsigned short*)alloc((size_t)1024 * 2);
    float*          sav    = (float*)alloc(4 * B_START * 32 * 4);

    k_cntb<<<NBUCK, 256, 0, stream>>>(ei, bhist);
    k_colscan<<<NBUCK, 256, 0, stream>>>(bhist, colsum);
    k_tiny<<<1, 256, 0, stream>>>(colsum, bbase);
    k_scat<<<NBUCK, 256, 0, stream>>>(ei, etype, bhist, bbase, arena);
    k_build<<<NBUCK, 256, 0, stream>>>(arena, bbase, off, pk_m, nv5, degpk);
    k_wprep<<<4, 256, 0, stream>>>(basis, comp, root, basis0, comp0, root0,
                                   wfh, wfr, wf0);
    k_cvt0<<<(N_NODES + 255) / 256, 256, 0, stream>>>(x, hb0);

    int nbGath = 8 * ((PART_SZ + 7) / 8);  // 12504 blocks
    int nbGemm = (N_NODES / 16 + 3) / 4;   // 1563 blocks

    // layer 0 (in=4)
    k_gath0<<<nbGath, 256, 0, stream>>>(hb0, x, pk_m, nv5, degpk, off, a0v);
    k_gemm0<<<nbGemm, 256, 0, stream>>>(a0v, wf0, bias0, h, hbuf);
    k_save<<<64, 256, 0, stream>>>(h, start, sav);
    // layers 1..3 (in=32)
    for (int l = 0; l < 3; l++) {
        k_gath32<<<nbGath, 256, 0, stream>>>(hbuf, pk_m, nv5, degpk, off, agg);
        k_gemm<<<nbGemm, 256, 0, stream>>>(agg, hbuf, wfh + (size_t)l * 5120,
                                           wfr + (size_t)l * 2048, bias + l * 32,
                                           h, hbuf);
        k_save<<<64, 256, 0, stream>>>(h, start, sav + (l + 1) * 16384);
    }

    k_mlp<<<B_START, 128, 0, stream>>>(sav, w1, b1, w2, b2, out);
}